// Round 1
// baseline (60.882 us; speedup 1.0000x reference)
//
#include <hip/hip_runtime.h>

#define NPTS 16384
#define NB 256
constexpr int THREADS = 1024;          // 16 waves per block, 1 block per CU
constexpr int EPT = 4;                 // elements per thread per chunk (float4)
constexpr int CHUNK = THREADS * EPT;   // 4096
constexpr int ITERS = NPTS / CHUNK;    // 4
constexpr int NWAVES = THREADS / 64;   // 16

__device__ __forceinline__ float4 ld4(const float* p) {
  return *reinterpret_cast<const float4*>(p);
}

__global__ __launch_bounds__(THREADS) void mpd_loss_kernel(
    const float* __restrict__ o3, const float* __restrict__ s3,
    const float* __restrict__ o2, const float* __restrict__ s2,
    const float* __restrict__ df, float* __restrict__ out) {
  const int b = blockIdx.x;
  const int t = threadIdx.x;
  const int lane = t & 63;
  const int wave = t >> 6;

  const float* r3p = s3 + (size_t)b * 3 * NPTS;
  const float* t3p = r3p + NPTS;
  const float* p3p = r3p + 2 * NPTS;
  const float* r2p = s2 + (size_t)b * 3 * NPTS;
  const float* t2p = r2p + NPTS;
  const float* p2p = r2p + 2 * NPTS;
  const float* dtp = df + (size_t)b * 2 * NPTS;
  const float* dpp = dtp + NPTS;

  __shared__ float wtot[3][NWAVES];
  __shared__ float redbuf[NWAVES];

  // origin difference = prefix element j=0; also the initial carry.
  const float ox = o3[b * 3 + 0] - o2[b * 3 + 0];
  const float oy = o3[b * 3 + 1] - o2[b * 3 + 1];
  const float oz = o3[b * 3 + 2] - o2[b * 3 + 2];
  float carry_x = ox, carry_y = oy, carry_z = oz;
  float acc = (t == 0) ? (fabsf(ox) + fabsf(oy) + fabsf(oz)) : 0.0f;

  // prefetch chunk 0
  int base = t * EPT;
  float4 cR3 = ld4(r3p + base), cT3 = ld4(t3p + base), cP3 = ld4(p3p + base);
  float4 cR2 = ld4(r2p + base), cT2 = ld4(t2p + base), cP2 = ld4(p2p + base);
  float4 cDT = ld4(dtp + base), cDP = ld4(dpp + base);

  #pragma unroll
  for (int it = 0; it < ITERS; ++it) {
    // software-pipeline: issue next chunk's loads before the scan phase
    float4 nR3, nT3, nP3, nR2, nT2, nP2, nDT, nDP;
    if (it + 1 < ITERS) {
      int nb = (it + 1) * CHUNK + t * EPT;
      nR3 = ld4(r3p + nb); nT3 = ld4(t3p + nb); nP3 = ld4(p3p + nb);
      nR2 = ld4(r2p + nb); nT2 = ld4(t2p + nb); nP2 = ld4(p2p + nb);
      nDT = ld4(dtp + nb); nDP = ld4(dpp + nb);
    }

    const float* fR3 = reinterpret_cast<const float*>(&cR3);
    const float* fT3 = reinterpret_cast<const float*>(&cT3);
    const float* fP3 = reinterpret_cast<const float*>(&cP3);
    const float* fR2 = reinterpret_cast<const float*>(&cR2);
    const float* fT2 = reinterpret_cast<const float*>(&cT2);
    const float* fP2 = reinterpret_cast<const float*>(&cP2);
    const float* fDT = reinterpret_cast<const float*>(&cDT);
    const float* fDP = reinterpret_cast<const float*>(&cDP);

    float px[EPT], py[EPT], pz[EPT];
    float sx = 0.f, sy = 0.f, sz = 0.f;
    #pragma unroll
    for (int e = 0; e < EPT; ++e) {
      float r3v = fR3[e];
      float th3 = fT3[e] + fDT[e];
      float ph3 = fP3[e] + fDP[e];
      float r2v = fR2[e];
      float th2 = fT2[e];
      float ph2 = fP2[e];
      float st3 = __sinf(th3), ct3 = __cosf(th3);
      float sp3 = __sinf(ph3), cp3 = __cosf(ph3);
      float st2 = __sinf(th2), ct2 = __cosf(th2);
      float sp2 = __sinf(ph2), cp2 = __cosf(ph2);
      float dx = r3v * st3 * cp3 - r2v * st2 * cp2;
      float dy = r3v * st3 * sp3 - r2v * st2 * sp2;
      float dz = r3v * ct3 - r2v * ct2;
      sx += dx; px[e] = sx;
      sy += dy; py[e] = sy;
      sz += dz; pz[e] = sz;
    }

    // wave-level inclusive scan of per-thread totals (3 independent chains)
    float ix = sx, iy = sy, iz = sz;
    #pragma unroll
    for (int off = 1; off < 64; off <<= 1) {
      float ax = __shfl_up(ix, off, 64);
      float ay = __shfl_up(iy, off, 64);
      float az = __shfl_up(iz, off, 64);
      if (lane >= off) { ix += ax; iy += ay; iz += az; }
    }
    float exs = ix - sx, eys = iy - sy, ezs = iz - sz;  // exclusive scan

    if (lane == 63) {
      wtot[0][wave] = ix; wtot[1][wave] = iy; wtot[2][wave] = iz;
    }
    __syncthreads();

    // per-wave offset + block total (uniform across threads of a wave)
    float wx = carry_x, wy = carry_y, wz = carry_z;
    float btx = 0.f, bty = 0.f, btz = 0.f;
    #pragma unroll
    for (int w = 0; w < NWAVES; ++w) {
      float vx = wtot[0][w], vy = wtot[1][w], vz = wtot[2][w];
      if (w < wave) { wx += vx; wy += vy; wz += vz; }
      btx += vx; bty += vy; btz += vz;
    }
    __syncthreads();  // wtot consumed; safe to overwrite next iteration
    carry_x += btx; carry_y += bty; carry_z += btz;

    float bx = wx + exs, by = wy + eys, bz = wz + ezs;
    #pragma unroll
    for (int e = 0; e < EPT; ++e) {
      acc += fabsf(bx + px[e]) + fabsf(by + py[e]) + fabsf(bz + pz[e]);
    }

    cR3 = nR3; cT3 = nT3; cP3 = nP3; cR2 = nR2;
    cT2 = nT2; cP2 = nP2; cDT = nDT; cDP = nDP;
  }

  // block reduction of acc
  #pragma unroll
  for (int off = 32; off > 0; off >>= 1) acc += __shfl_down(acc, off, 64);
  if (lane == 0) redbuf[wave] = acc;
  __syncthreads();
  if (t == 0) {
    float s = 0.f;
    #pragma unroll
    for (int w = 0; w < NWAVES; ++w) s += redbuf[w];
    atomicAdd(out, s * (1.0f / (float)(NPTS + 1)));
  }
}

extern "C" void kernel_launch(void* const* d_in, const int* in_sizes, int n_in,
                              void* d_out, int out_size, void* d_ws, size_t ws_size,
                              hipStream_t stream) {
  const float* o3 = (const float*)d_in[0];  // origin_3D      (B,3,1)
  const float* s3 = (const float*)d_in[1];  // spherical_3D   (B,3,N)
  const float* o2 = (const float*)d_in[2];  // origin_2D      (B,3,1)
  const float* s2 = (const float*)d_in[3];  // spherical_2D   (B,3,N)
  const float* df = (const float*)d_in[4];  // deformation    (B,2,N)
  float* out = (float*)d_out;

  // harness does not re-zero d_out between timed replays
  hipMemsetAsync(out, 0, sizeof(float) * out_size, stream);
  mpd_loss_kernel<<<NB, THREADS, 0, stream>>>(o3, s3, o2, s2, df, out);
}